// Round 5
// baseline (598.701 us; speedup 1.0000x reference)
//
#include <hip/hip_runtime.h>

// GCN 2-layer. Edges bucket-partitioned by dst (782 buckets of 128 nodes),
// then counting-sorted per bucket into a fully dst-sorted src list + row_ptr.
// Aggregation = register-accumulating gather (float4), no fp32 atomics anywhere.
// GEMMs: register-tiled (2x12 / 2x8 per thread), transposed-X LDS staging.
// out = GCNConv(relu(GCNConv(x,W1,b1)), W2, b2); N=100k, E=1.6M, 64->48->32.

#define NN 100000
#define NE 1600000
#define NPB 128                         // nodes per bucket
#define NBUCK ((NN + NPB - 1) / NPB)    // 782
#define PBITS 17                        // src fits in 17 bits
#define PMASK ((1 << PBITS) - 1)
#define PART_B 512
#define EPT 32
#define PART_G ((NE + PART_B * EPT - 1) / (PART_B * EPT))   // 98
#define CAP 4096                        // LDS staging per bucket (mean 2048)

__global__ void k_zero_b(int* __restrict__ bcnt) {
    int i = threadIdx.x;
    if (i < NBUCK) bcnt[i] = 0;
}

// per-bucket edge histogram (LDS-staged, int atomics only)
__global__ void k_hist(const int* __restrict__ dst, int* __restrict__ bcnt) {
    __shared__ int h[NBUCK];
    for (int i = threadIdx.x; i < NBUCK; i += blockDim.x) h[i] = 0;
    __syncthreads();
    int base = blockIdx.x * (PART_B * EPT);
    for (int k = 0; k < EPT; ++k) {
        int e = base + k * PART_B + threadIdx.x;
        if (e < NE) atomicAdd(&h[dst[e] >> 7], 1);
    }
    __syncthreads();
    for (int i = threadIdx.x; i < NBUCK; i += blockDim.x)
        if (h[i]) atomicAdd(&bcnt[i], h[i]);
}

// single-block exclusive scan over 782 bucket counts; row_ptr[NN] = NE
__global__ void k_scan(const int* __restrict__ bcnt, int* __restrict__ bbase,
                       int* __restrict__ gcursor, int* __restrict__ row_ptr) {
    __shared__ int sm[1024];
    int t = threadIdx.x;
    int v = (t < NBUCK) ? bcnt[t] : 0;
    sm[t] = v; __syncthreads();
    for (int off = 1; off < 1024; off <<= 1) {
        int xv = (t >= off) ? sm[t - off] : 0;
        __syncthreads();
        sm[t] += xv;
        __syncthreads();
    }
    if (t < NBUCK) { int ex = sm[t] - v; bbase[t] = ex; gcursor[t] = ex; }
    if (t == 0) { bbase[NBUCK] = NE; row_ptr[NN] = NE; }
}

// partition edges into bucket order; packed = src | (dst_local << PBITS)
__global__ void k_part(const int* __restrict__ src, const int* __restrict__ dst,
                       int* __restrict__ gcursor, int* __restrict__ packed) {
    __shared__ int h[NBUCK];
    __shared__ int base[NBUCK];
    for (int i = threadIdx.x; i < NBUCK; i += blockDim.x) h[i] = 0;
    __syncthreads();
    int ebase = blockIdx.x * (PART_B * EPT);
    for (int k = 0; k < EPT; ++k) {
        int e = ebase + k * PART_B + threadIdx.x;
        if (e < NE) atomicAdd(&h[dst[e] >> 7], 1);
    }
    __syncthreads();
    for (int i = threadIdx.x; i < NBUCK; i += blockDim.x) {
        int c = h[i];
        if (c) base[i] = atomicAdd(&gcursor[i], c);
        h[i] = 0;
    }
    __syncthreads();
    for (int k = 0; k < EPT; ++k) {
        int e = ebase + k * PART_B + threadIdx.x;
        if (e < NE) {
            int d = dst[e];
            int b = d >> 7;
            int r = atomicAdd(&h[b], 1);
            packed[base[b] + r] = src[e] | ((d & (NPB - 1)) << PBITS);
        }
    }
}

// per-bucket counting sort -> fully dst-sorted src list, row_ptr, dinv.
__global__ void k_bsort(const int* __restrict__ packed, const int* __restrict__ bbase,
                        int* __restrict__ srcsort, int* __restrict__ row_ptr,
                        float* __restrict__ dinv) {
    __shared__ int stage[CAP];
    __shared__ int cnt[NPB];
    __shared__ int pos[NPB];
    int tid = threadIdx.x, b = blockIdx.x;
    int e0 = bbase[b], e1 = bbase[b + 1], sz = e1 - e0;
    if (tid < NPB) cnt[tid] = 0;
    __syncthreads();
    for (int i = tid; i < sz; i += 256) {
        int w = packed[e0 + i];
        if (i < CAP) stage[i] = w;
        atomicAdd(&cnt[w >> PBITS], 1);
    }
    __syncthreads();
    if (tid < NPB) pos[tid] = cnt[tid];
    __syncthreads();
    for (int off = 1; off < NPB; off <<= 1) {           // inclusive scan of cnt
        int v = (tid < NPB && tid >= off) ? pos[tid - off] : 0;
        __syncthreads();
        if (tid < NPB) pos[tid] += v;
        __syncthreads();
    }
    int node = b * NPB + tid;
    if (tid < NPB) {
        int ex = pos[tid] - cnt[tid];                   // exclusive
        if (node < NN) {
            row_ptr[node] = e0 + ex;
            dinv[node] = rsqrtf((float)(cnt[tid] + 1)); // +1 self-loop
        }
        cnt[tid] = ex;                                  // reuse as cursor
    }
    __syncthreads();
    for (int i = tid; i < sz; i += 256) {
        int w = (i < CAP) ? stage[i] : packed[e0 + i];
        int dl = w >> PBITS;
        int p = atomicAdd(&cnt[dl], 1);
        srcsort[e0 + p] = w & PMASK;
    }
}

// Register-tiled GEMM: Hs[M,NC] = f(X[M,K]) @ W[K,NC] * dinv[row]
// f = relu(x + bin) when RELU_IN. Block = 256 thr, tile = 128 rows.
// Thread = 2 rows x CPT cols. Xt staged transposed (stride XS), W staged raw.
template <int K, int NC, int CPT, bool RELU_IN>
__global__ void k_gemm(const float* __restrict__ X, const float* __restrict__ W,
                       const float* __restrict__ bin, const float* __restrict__ dinv,
                       float* __restrict__ H, int M) {
    constexpr int CG = NC / CPT;     // col groups (4)
    constexpr int MT = (256 / CG) * 2;   // 128 rows per block
    constexpr int XS = MT + 2;       // padded Xt row stride (even, breaks pow2)
    constexpr int KF4 = K / 4;
    __shared__ float xt[K * XS];
    __shared__ float w[K * NC];
    int tid = threadIdx.x;
    int R0 = blockIdx.x * MT;

    for (int i = tid; i < K * NC; i += 256) w[i] = W[i];
    // stage X transposed: xt[k][r] = f(X[R0+r][k])
    for (int i = tid; i < MT * KF4; i += 256) {
        int r = i / KF4, k4 = i - r * KF4;
        int gr = R0 + r;
        float4 v = make_float4(0.f, 0.f, 0.f, 0.f);
        if (gr < M) v = ((const float4*)X)[(size_t)gr * KF4 + k4];
        if (RELU_IN) {
            v.x = fmaxf(v.x + bin[k4 * 4 + 0], 0.f);
            v.y = fmaxf(v.y + bin[k4 * 4 + 1], 0.f);
            v.z = fmaxf(v.z + bin[k4 * 4 + 2], 0.f);
            v.w = fmaxf(v.w + bin[k4 * 4 + 3], 0.f);
        }
        xt[(k4 * 4 + 0) * XS + r] = v.x;
        xt[(k4 * 4 + 1) * XS + r] = v.y;
        xt[(k4 * 4 + 2) * XS + r] = v.z;
        xt[(k4 * 4 + 3) * XS + r] = v.w;
    }
    __syncthreads();

    int tc = tid % CG, tr = tid / CG;
    int r0 = 2 * tr, c0 = tc * CPT;
    float acc[2][CPT];
#pragma unroll
    for (int rr = 0; rr < 2; ++rr)
#pragma unroll
        for (int j = 0; j < CPT; ++j) acc[rr][j] = 0.f;

    for (int k = 0; k < K; ++k) {
        float2 xv = *(const float2*)&xt[k * XS + r0];   // conflict-free b64
#pragma unroll
        for (int q = 0; q < CPT / 4; ++q) {
            float4 wv = *(const float4*)&w[k * NC + c0 + q * 4];  // bcast b128
            acc[0][q*4+0] = fmaf(xv.x, wv.x, acc[0][q*4+0]);
            acc[0][q*4+1] = fmaf(xv.x, wv.y, acc[0][q*4+1]);
            acc[0][q*4+2] = fmaf(xv.x, wv.z, acc[0][q*4+2]);
            acc[0][q*4+3] = fmaf(xv.x, wv.w, acc[0][q*4+3]);
            acc[1][q*4+0] = fmaf(xv.y, wv.x, acc[1][q*4+0]);
            acc[1][q*4+1] = fmaf(xv.y, wv.y, acc[1][q*4+1]);
            acc[1][q*4+2] = fmaf(xv.y, wv.z, acc[1][q*4+2]);
            acc[1][q*4+3] = fmaf(xv.y, wv.w, acc[1][q*4+3]);
        }
    }
#pragma unroll
    for (int rr = 0; rr < 2; ++rr) {
        int gr = R0 + r0 + rr;
        if (gr >= M) continue;
        float d = dinv[gr];
#pragma unroll
        for (int q = 0; q < CPT / 4; ++q) {
            float4 o;
            o.x = acc[rr][q*4+0] * d; o.y = acc[rr][q*4+1] * d;
            o.z = acc[rr][q*4+2] * d; o.w = acc[rr][q*4+3] * d;
            ((float4*)H)[((size_t)gr * NC + c0) / 4 + q] = o;
        }
    }
}

// out[i,:] = dinv[i] * (Hs[i,:] + sum_{e in row i} Hs[src_e,:]) (+ b)
template <int NC, bool BIAS>
__global__ void k_agg(const float* __restrict__ Hs, const int* __restrict__ row_ptr,
                      const int* __restrict__ srcsort, const float* __restrict__ dinv,
                      const float* __restrict__ bias, float* __restrict__ out) {
    constexpr int Q = NC / 4;
    int idx = blockIdx.x * blockDim.x + threadIdx.x;
    if (idx >= NN * Q) return;
    int r = idx / Q, q = idx - r * Q;
    const float4* H4 = (const float4*)Hs;
    float4 a = H4[(size_t)r * Q + q];                   // self-loop term
    float ax = a.x, ay = a.y, az = a.z, aw = a.w;
    int e0 = row_ptr[r], e1 = row_ptr[r + 1];
    for (int e = e0; e < e1; ++e) {
        int s = srcsort[e];
        float4 v = H4[(size_t)s * Q + q];
        ax += v.x; ay += v.y; az += v.z; aw += v.w;
    }
    float d = dinv[r];
    ax *= d; ay *= d; az *= d; aw *= d;
    if (BIAS) {
        const float4* b4 = (const float4*)bias;
        float4 bv = b4[q];
        ax += bv.x; ay += bv.y; az += bv.z; aw += bv.w;
    }
    float4 o = {ax, ay, az, aw};
    ((float4*)out)[(size_t)r * Q + q] = o;
}

extern "C" void kernel_launch(void* const* d_in, const int* in_sizes, int n_in,
                              void* d_out, int out_size, void* d_ws, size_t ws_size,
                              hipStream_t stream) {
    const float* x  = (const float*)d_in[0];
    const int*   ei = (const int*)d_in[1];   // [2,NE] int32
    const float* W1 = (const float*)d_in[2];
    const float* b1 = (const float*)d_in[3];
    const float* W2 = (const float*)d_in[4];
    const float* b2 = (const float*)d_in[5];
    float* out = (float*)d_out;

    const int* src = ei;
    const int* dst = ei + NE;

    char* p = (char*)d_ws;
    auto take = [&](size_t elems) { void* q = p; p += ((elems * 4 + 255) & ~255ull); return q; };
    int*   bcnt    = (int*)take(NBUCK);
    int*   bbase   = (int*)take(NBUCK + 1);
    int*   gcursor = (int*)take(NBUCK);
    int*   row_ptr = (int*)take(NN + 1);
    float* dinv    = (float*)take(NN);
    int*   srcsort = (int*)take(NE);
    float* Hs      = (float*)take((size_t)NN * 48);
    float* agg1    = (float*)take((size_t)NN * 48);
    int*   packed  = (int*)agg1;   // alias: packed dead before agg1 is written
    float* Hs2     = Hs;           // Hs dead after agg1

    const int B = 256;
    const int GB = (NN + 127) / 128;   // 782 gemm blocks
    // --- dst-sort of edges ---
    k_zero_b<<<1, 1024, 0, stream>>>(bcnt);
    k_hist<<<PART_G, PART_B, 0, stream>>>(dst, bcnt);
    k_scan<<<1, 1024, 0, stream>>>(bcnt, bbase, gcursor, row_ptr);
    k_part<<<PART_G, PART_B, 0, stream>>>(src, dst, gcursor, packed);
    k_bsort<<<NBUCK, 256, 0, stream>>>(packed, bbase, srcsort, row_ptr, dinv);

    // --- layer 1 ---
    k_gemm<64, 48, 12, false><<<GB, 256, 0, stream>>>(x, W1, nullptr, dinv, Hs, NN);
    k_agg<48, false><<<(NN * 12 + B - 1) / B, B, 0, stream>>>(Hs, row_ptr, srcsort, dinv, nullptr, agg1);

    // --- layer 2 (bias1+relu fused into GEMM staging) ---
    k_gemm<48, 32, 8, true><<<GB, 256, 0, stream>>>(agg1, W2, b1, dinv, Hs2, NN);
    k_agg<32, true><<<(NN * 8 + B - 1) / B, B, 0, stream>>>(Hs2, row_ptr, srcsort, dinv, b2, out);
}

// Round 6
// 290.441 us; speedup vs baseline: 2.0613x; 2.0613x over previous
//
#include <hip/hip_runtime.h>

// GCN 2-layer. Edges bucket-partitioned by dst (782 buckets of 128 nodes),
// then counting-sorted per bucket into a fully dst-sorted src list + row_ptr.
// Aggregation = register-accumulating gather (float4), no fp32 atomics anywhere.
// GEMMs: register-tiled 2xCPT per thread, X from global (L1 broadcast),
// W as float4 LDS broadcast, bounded unroll (round-5's transposed-X staging
// caused ~850 MB of scratch spill traffic -- do not reintroduce).
// out = GCNConv(relu(GCNConv(x,W1,b1)), W2, b2); N=100k, E=1.6M, 64->48->32.

#define NN 100000
#define NE 1600000
#define NPB 128                         // nodes per bucket
#define NBUCK ((NN + NPB - 1) / NPB)    // 782
#define PBITS 17                        // src fits in 17 bits
#define PMASK ((1 << PBITS) - 1)
#define PART_B 512
#define EPT 32
#define PART_G ((NE + PART_B * EPT - 1) / (PART_B * EPT))   // 98
#define CAP 4096                        // LDS staging per bucket (mean 2048)

__global__ void k_zero_b(int* __restrict__ bcnt) {
    int i = threadIdx.x;
    if (i < NBUCK) bcnt[i] = 0;
}

// per-bucket edge histogram (LDS-staged, int atomics only)
__global__ void k_hist(const int* __restrict__ dst, int* __restrict__ bcnt) {
    __shared__ int h[NBUCK];
    for (int i = threadIdx.x; i < NBUCK; i += blockDim.x) h[i] = 0;
    __syncthreads();
    int base = blockIdx.x * (PART_B * EPT);
    for (int k = 0; k < EPT; ++k) {
        int e = base + k * PART_B + threadIdx.x;
        if (e < NE) atomicAdd(&h[dst[e] >> 7], 1);
    }
    __syncthreads();
    for (int i = threadIdx.x; i < NBUCK; i += blockDim.x)
        if (h[i]) atomicAdd(&bcnt[i], h[i]);
}

// single-block exclusive scan over 782 bucket counts; row_ptr[NN] = NE
__global__ void k_scan(const int* __restrict__ bcnt, int* __restrict__ bbase,
                       int* __restrict__ gcursor, int* __restrict__ row_ptr) {
    __shared__ int sm[1024];
    int t = threadIdx.x;
    int v = (t < NBUCK) ? bcnt[t] : 0;
    sm[t] = v; __syncthreads();
    for (int off = 1; off < 1024; off <<= 1) {
        int xv = (t >= off) ? sm[t - off] : 0;
        __syncthreads();
        sm[t] += xv;
        __syncthreads();
    }
    if (t < NBUCK) { int ex = sm[t] - v; bbase[t] = ex; gcursor[t] = ex; }
    if (t == 0) { bbase[NBUCK] = NE; row_ptr[NN] = NE; }
}

// partition edges into bucket order; packed = src | (dst_local << PBITS)
__global__ void k_part(const int* __restrict__ src, const int* __restrict__ dst,
                       int* __restrict__ gcursor, int* __restrict__ packed) {
    __shared__ int h[NBUCK];
    __shared__ int base[NBUCK];
    for (int i = threadIdx.x; i < NBUCK; i += blockDim.x) h[i] = 0;
    __syncthreads();
    int ebase = blockIdx.x * (PART_B * EPT);
    for (int k = 0; k < EPT; ++k) {
        int e = ebase + k * PART_B + threadIdx.x;
        if (e < NE) atomicAdd(&h[dst[e] >> 7], 1);
    }
    __syncthreads();
    for (int i = threadIdx.x; i < NBUCK; i += blockDim.x) {
        int c = h[i];
        if (c) base[i] = atomicAdd(&gcursor[i], c);
        h[i] = 0;
    }
    __syncthreads();
    for (int k = 0; k < EPT; ++k) {
        int e = ebase + k * PART_B + threadIdx.x;
        if (e < NE) {
            int d = dst[e];
            int b = d >> 7;
            int r = atomicAdd(&h[b], 1);
            packed[base[b] + r] = src[e] | ((d & (NPB - 1)) << PBITS);
        }
    }
}

// per-bucket counting sort -> fully dst-sorted src list, row_ptr, dinv.
__global__ void k_bsort(const int* __restrict__ packed, const int* __restrict__ bbase,
                        int* __restrict__ srcsort, int* __restrict__ row_ptr,
                        float* __restrict__ dinv) {
    __shared__ int stage[CAP];
    __shared__ int cnt[NPB];
    __shared__ int pos[NPB];
    int tid = threadIdx.x, b = blockIdx.x;
    int e0 = bbase[b], e1 = bbase[b + 1], sz = e1 - e0;
    if (tid < NPB) cnt[tid] = 0;
    __syncthreads();
    for (int i = tid; i < sz; i += 256) {
        int w = packed[e0 + i];
        if (i < CAP) stage[i] = w;
        atomicAdd(&cnt[w >> PBITS], 1);
    }
    __syncthreads();
    if (tid < NPB) pos[tid] = cnt[tid];
    __syncthreads();
    for (int off = 1; off < NPB; off <<= 1) {           // inclusive scan of cnt
        int v = (tid < NPB && tid >= off) ? pos[tid - off] : 0;
        __syncthreads();
        if (tid < NPB) pos[tid] += v;
        __syncthreads();
    }
    int node = b * NPB + tid;
    if (tid < NPB) {
        int ex = pos[tid] - cnt[tid];                   // exclusive
        if (node < NN) {
            row_ptr[node] = e0 + ex;
            dinv[node] = rsqrtf((float)(cnt[tid] + 1)); // +1 self-loop
        }
        cnt[tid] = ex;                                  // reuse as cursor
    }
    __syncthreads();
    for (int i = tid; i < sz; i += 256) {
        int w = (i < CAP) ? stage[i] : packed[e0 + i];
        int dl = w >> PBITS;
        int p = atomicAdd(&cnt[dl], 1);
        srcsort[e0 + p] = w & PMASK;
    }
}

// Register-tiled GEMM: Hs[M,NC] = f(X[M,K]) @ W[K,NC] * dinv[row]
// f = relu(x + bin) when RELU_IN. Block = 256 thr = 128-row tile.
// Thread = 2 rows x CPT cols; X float4 from global (4-lane L1 broadcast),
// W float4 from LDS (conflict-free broadcast). Bounded unroll: no spills.
template <int K, int NC, int CPT, bool RELU_IN>
__global__ __launch_bounds__(256) void
k_gemm(const float* __restrict__ X, const float* __restrict__ W,
       const float* __restrict__ bin, const float* __restrict__ dinv,
       float* __restrict__ H, int M) {
    constexpr int CG = NC / CPT;         // 4 col groups
    constexpr int MT = (256 / CG) * 2;   // 128 rows per block
    constexpr int KF4 = K / 4;
    __shared__ float w[K * NC];
    __shared__ float bb[K];
    int tid = threadIdx.x;
    int R0 = blockIdx.x * MT;
    for (int i = tid; i < K * NC; i += 256) w[i] = W[i];
    if (RELU_IN)
        for (int i = tid; i < K; i += 256) bb[i] = bin[i];
    __syncthreads();

    int tc = tid % CG, tr = tid / CG;
    int r0 = R0 + 2 * tr, r1 = r0 + 1;
    int c0 = tc * CPT;
    bool ok0 = r0 < M, ok1 = r1 < M;
    const float4* X4 = (const float4*)X;
    const float4 z4 = make_float4(0.f, 0.f, 0.f, 0.f);

    float acc[2][CPT];
#pragma unroll
    for (int rr = 0; rr < 2; ++rr)
#pragma unroll
        for (int j = 0; j < CPT; ++j) acc[rr][j] = 0.f;

#pragma unroll 2
    for (int k4 = 0; k4 < KF4; ++k4) {
        float4 xa = ok0 ? X4[(size_t)r0 * KF4 + k4] : z4;
        float4 xb = ok1 ? X4[(size_t)r1 * KF4 + k4] : z4;
        float ar[4] = {xa.x, xa.y, xa.z, xa.w};
        float br[4] = {xb.x, xb.y, xb.z, xb.w};
#pragma unroll
        for (int j = 0; j < 4; ++j) {
            float va = ar[j], vb = br[j];
            if (RELU_IN) {
                float bv = bb[4 * k4 + j];
                va = fmaxf(va + bv, 0.f);
                vb = fmaxf(vb + bv, 0.f);
            }
#pragma unroll
            for (int q = 0; q < CPT / 4; ++q) {
                float4 wv = *(const float4*)&w[(4 * k4 + j) * NC + c0 + 4 * q];
                acc[0][q*4+0] = fmaf(va, wv.x, acc[0][q*4+0]);
                acc[0][q*4+1] = fmaf(va, wv.y, acc[0][q*4+1]);
                acc[0][q*4+2] = fmaf(va, wv.z, acc[0][q*4+2]);
                acc[0][q*4+3] = fmaf(va, wv.w, acc[0][q*4+3]);
                acc[1][q*4+0] = fmaf(vb, wv.x, acc[1][q*4+0]);
                acc[1][q*4+1] = fmaf(vb, wv.y, acc[1][q*4+1]);
                acc[1][q*4+2] = fmaf(vb, wv.z, acc[1][q*4+2]);
                acc[1][q*4+3] = fmaf(vb, wv.w, acc[1][q*4+3]);
            }
        }
    }
#pragma unroll
    for (int rr = 0; rr < 2; ++rr) {
        int gr = r0 + rr;
        if (gr >= M) continue;
        float d = dinv[gr];
#pragma unroll
        for (int q = 0; q < CPT / 4; ++q) {
            float4 o;
            o.x = acc[rr][q*4+0] * d; o.y = acc[rr][q*4+1] * d;
            o.z = acc[rr][q*4+2] * d; o.w = acc[rr][q*4+3] * d;
            ((float4*)H)[((size_t)gr * NC + c0) / 4 + q] = o;
        }
    }
}

// out[i,:] = dinv[i] * (Hs[i,:] + sum_{e in row i} Hs[src_e,:]) (+ b)
template <int NC, bool BIAS>
__global__ void k_agg(const float* __restrict__ Hs, const int* __restrict__ row_ptr,
                      const int* __restrict__ srcsort, const float* __restrict__ dinv,
                      const float* __restrict__ bias, float* __restrict__ out) {
    constexpr int Q = NC / 4;
    int idx = blockIdx.x * blockDim.x + threadIdx.x;
    if (idx >= NN * Q) return;
    int r = idx / Q, q = idx - r * Q;
    const float4* H4 = (const float4*)Hs;
    float4 a = H4[(size_t)r * Q + q];                   // self-loop term
    float ax = a.x, ay = a.y, az = a.z, aw = a.w;
    int e0 = row_ptr[r], e1 = row_ptr[r + 1];
    for (int e = e0; e < e1; ++e) {
        int s = srcsort[e];
        float4 v = H4[(size_t)s * Q + q];
        ax += v.x; ay += v.y; az += v.z; aw += v.w;
    }
    float d = dinv[r];
    ax *= d; ay *= d; az *= d; aw *= d;
    if (BIAS) {
        const float4* b4 = (const float4*)bias;
        float4 bv = b4[q];
        ax += bv.x; ay += bv.y; az += bv.z; aw += bv.w;
    }
    float4 o = {ax, ay, az, aw};
    ((float4*)out)[(size_t)r * Q + q] = o;
}

extern "C" void kernel_launch(void* const* d_in, const int* in_sizes, int n_in,
                              void* d_out, int out_size, void* d_ws, size_t ws_size,
                              hipStream_t stream) {
    const float* x  = (const float*)d_in[0];
    const int*   ei = (const int*)d_in[1];   // [2,NE] int32
    const float* W1 = (const float*)d_in[2];
    const float* b1 = (const float*)d_in[3];
    const float* W2 = (const float*)d_in[4];
    const float* b2 = (const float*)d_in[5];
    float* out = (float*)d_out;

    const int* src = ei;
    const int* dst = ei + NE;

    char* p = (char*)d_ws;
    auto take = [&](size_t elems) { void* q = p; p += ((elems * 4 + 255) & ~255ull); return q; };
    int*   bcnt    = (int*)take(NBUCK);
    int*   bbase   = (int*)take(NBUCK + 1);
    int*   gcursor = (int*)take(NBUCK);
    int*   row_ptr = (int*)take(NN + 1);
    float* dinv    = (float*)take(NN);
    int*   srcsort = (int*)take(NE);
    float* Hs      = (float*)take((size_t)NN * 48);
    float* agg1    = (float*)take((size_t)NN * 48);
    int*   packed  = (int*)agg1;   // alias: packed dead before agg1 is written
    float* Hs2     = Hs;           // Hs dead after agg1

    const int B = 256;
    const int GB = (NN + 127) / 128;   // 782 gemm blocks
    // --- dst-sort of edges ---
    k_zero_b<<<1, 1024, 0, stream>>>(bcnt);
    k_hist<<<PART_G, PART_B, 0, stream>>>(dst, bcnt);
    k_scan<<<1, 1024, 0, stream>>>(bcnt, bbase, gcursor, row_ptr);
    k_part<<<PART_G, PART_B, 0, stream>>>(src, dst, gcursor, packed);
    k_bsort<<<NBUCK, 256, 0, stream>>>(packed, bbase, srcsort, row_ptr, dinv);

    // --- layer 1 ---
    k_gemm<64, 48, 12, false><<<GB, 256, 0, stream>>>(x, W1, nullptr, dinv, Hs, NN);
    k_agg<48, false><<<(NN * 12 + B - 1) / B, B, 0, stream>>>(Hs, row_ptr, srcsort, dinv, nullptr, agg1);

    // --- layer 2 (bias1+relu fused into GEMM input read) ---
    k_gemm<48, 32, 8, true><<<GB, 256, 0, stream>>>(agg1, W2, b1, dinv, Hs2, NN);
    k_agg<32, true><<<(NN * 8 + B - 1) / B, B, 0, stream>>>(Hs2, row_ptr, srcsort, dinv, b2, out);
}

// Round 7
// 280.153 us; speedup vs baseline: 2.1371x; 1.0367x over previous
//
#include <hip/hip_runtime.h>

// GCN 2-layer. Edges bucket-partitioned by dst (782 buckets of 128 nodes),
// then counting-sorted per bucket by (dst_local, src>>14): rows are contiguous
// AND each row's edges are grouped by 16k-node src chunk (2.4 MB of Hs per
// chunk fits a 4 MB XCD-L2), so the agg gather sweeps src space monotonically
// and concurrent waves share an L2-resident working set.
// Aggregation = register-accumulating gather (float4), no fp32 atomics.
// GEMMs: register-tiled 2xCPT, X from global (L1 broadcast), W in LDS
// (round-5 lesson: transposed-X LDS staging + full unroll => 850 MB of spills).
// out = GCNConv(relu(GCNConv(x,W1,b1)), W2, b2); N=100k, E=1.6M, 64->48->32.

#define NN 100000
#define NE 1600000
#define NPB 128                         // nodes per bucket
#define NBUCK ((NN + NPB - 1) / NPB)    // 782
#define PBITS 17                        // src fits in 17 bits
#define PMASK ((1 << PBITS) - 1)
#define CHB 3                           // log2 src chunks
#define CHS 14                          // chunk = src >> 14 (16384 nodes/chunk)
#define NKEY (NPB << CHB)               // 1024 sort keys per bucket
#define PART_B 512
#define EPT 32
#define PART_G ((NE + PART_B * EPT - 1) / (PART_B * EPT))   // 98
#define CAP 4096                        // LDS staging per bucket (mean 2048)

__global__ void k_zero_b(int* __restrict__ bcnt) {
    int i = threadIdx.x;
    if (i < NBUCK) bcnt[i] = 0;
}

// per-bucket edge histogram (LDS-staged, int atomics only)
__global__ void k_hist(const int* __restrict__ dst, int* __restrict__ bcnt) {
    __shared__ int h[NBUCK];
    for (int i = threadIdx.x; i < NBUCK; i += blockDim.x) h[i] = 0;
    __syncthreads();
    int base = blockIdx.x * (PART_B * EPT);
    for (int k = 0; k < EPT; ++k) {
        int e = base + k * PART_B + threadIdx.x;
        if (e < NE) atomicAdd(&h[dst[e] >> 7], 1);
    }
    __syncthreads();
    for (int i = threadIdx.x; i < NBUCK; i += blockDim.x)
        if (h[i]) atomicAdd(&bcnt[i], h[i]);
}

// single-block exclusive scan over 782 bucket counts; row_ptr[NN] = NE
__global__ void k_scan(const int* __restrict__ bcnt, int* __restrict__ bbase,
                       int* __restrict__ gcursor, int* __restrict__ row_ptr) {
    __shared__ int sm[1024];
    int t = threadIdx.x;
    int v = (t < NBUCK) ? bcnt[t] : 0;
    sm[t] = v; __syncthreads();
    for (int off = 1; off < 1024; off <<= 1) {
        int xv = (t >= off) ? sm[t - off] : 0;
        __syncthreads();
        sm[t] += xv;
        __syncthreads();
    }
    if (t < NBUCK) { int ex = sm[t] - v; bbase[t] = ex; gcursor[t] = ex; }
    if (t == 0) { bbase[NBUCK] = NE; row_ptr[NN] = NE; }
}

// partition edges into bucket order; packed = src | (dst_local << PBITS)
__global__ void k_part(const int* __restrict__ src, const int* __restrict__ dst,
                       int* __restrict__ gcursor, int* __restrict__ packed) {
    __shared__ int h[NBUCK];
    __shared__ int base[NBUCK];
    for (int i = threadIdx.x; i < NBUCK; i += blockDim.x) h[i] = 0;
    __syncthreads();
    int ebase = blockIdx.x * (PART_B * EPT);
    for (int k = 0; k < EPT; ++k) {
        int e = ebase + k * PART_B + threadIdx.x;
        if (e < NE) atomicAdd(&h[dst[e] >> 7], 1);
    }
    __syncthreads();
    for (int i = threadIdx.x; i < NBUCK; i += blockDim.x) {
        int c = h[i];
        if (c) base[i] = atomicAdd(&gcursor[i], c);
        h[i] = 0;
    }
    __syncthreads();
    for (int k = 0; k < EPT; ++k) {
        int e = ebase + k * PART_B + threadIdx.x;
        if (e < NE) {
            int d = dst[e];
            int b = d >> 7;
            int r = atomicAdd(&h[b], 1);
            packed[base[b] + r] = src[e] | ((d & (NPB - 1)) << PBITS);
        }
    }
}

// per-bucket counting sort by (dst_local, src_chunk) -> srcsort, row_ptr, dinv.
__global__ void k_bsort(const int* __restrict__ packed, const int* __restrict__ bbase,
                        int* __restrict__ srcsort, int* __restrict__ row_ptr,
                        float* __restrict__ dinv) {
    __shared__ int stage[CAP];          // 16 KB
    __shared__ int cnt[NKEY];           // 4 KB  (counts -> excl starts -> cursors)
    __shared__ int tsum[256];           // 1 KB
    int tid = threadIdx.x, b = blockIdx.x;
    int e0 = bbase[b], e1 = bbase[b + 1], sz = e1 - e0;
    for (int i = tid; i < NKEY; i += 256) cnt[i] = 0;
    __syncthreads();
    for (int i = tid; i < sz; i += 256) {
        int w = packed[e0 + i];
        if (i < CAP) stage[i] = w;
        int key = ((w >> PBITS) << CHB) | ((w & PMASK) >> CHS);
        atomicAdd(&cnt[key], 1);
    }
    __syncthreads();
    // exclusive scan over NKEY=1024: each thread owns 4 consecutive keys
    int k0 = tid * 4;
    int c0 = cnt[k0], c1 = cnt[k0 + 1], c2 = cnt[k0 + 2], c3 = cnt[k0 + 3];
    int loc = c0 + c1 + c2 + c3;
    tsum[tid] = loc;
    __syncthreads();
    for (int off = 1; off < 256; off <<= 1) {
        int v = (tid >= off) ? tsum[tid - off] : 0;
        __syncthreads();
        tsum[tid] += v;
        __syncthreads();
    }
    int base = tsum[tid] - loc;         // exclusive across threads
    cnt[k0]     = base;
    cnt[k0 + 1] = base + c0;
    cnt[k0 + 2] = base + c0 + c1;
    cnt[k0 + 3] = base + c0 + c1 + c2;
    __syncthreads();
    // row starts / degrees BEFORE cursors get bumped
    if (tid < NPB) {
        int node = b * NPB + tid;
        int rs = cnt[tid << CHB];
        int re = (tid == NPB - 1) ? sz : cnt[(tid + 1) << CHB];
        if (node < NN) {
            row_ptr[node] = e0 + rs;
            dinv[node] = rsqrtf((float)(re - rs + 1));   // +1 self-loop
        }
    }
    __syncthreads();
    for (int i = tid; i < sz; i += 256) {
        int w = (i < CAP) ? stage[i] : packed[e0 + i];
        int key = ((w >> PBITS) << CHB) | ((w & PMASK) >> CHS);
        int p = atomicAdd(&cnt[key], 1);
        srcsort[e0 + p] = w & PMASK;
    }
}

// Register-tiled GEMM: Hs[M,NC] = f(X[M,K]) @ W[K,NC] * dinv[row]
// f = relu(x + bin) when RELU_IN. Block = 256 thr = 128-row tile.
template <int K, int NC, int CPT, bool RELU_IN>
__global__ __launch_bounds__(256) void
k_gemm(const float* __restrict__ X, const float* __restrict__ W,
       const float* __restrict__ bin, const float* __restrict__ dinv,
       float* __restrict__ H, int M) {
    constexpr int CG = NC / CPT;         // 4 col groups
    constexpr int MT = (256 / CG) * 2;   // 128 rows per block
    constexpr int KF4 = K / 4;
    __shared__ float w[K * NC];
    __shared__ float bb[K];
    int tid = threadIdx.x;
    int R0 = blockIdx.x * MT;
    for (int i = tid; i < K * NC; i += 256) w[i] = W[i];
    if (RELU_IN)
        for (int i = tid; i < K; i += 256) bb[i] = bin[i];
    __syncthreads();

    int tc = tid % CG, tr = tid / CG;
    int r0 = R0 + 2 * tr, r1 = r0 + 1;
    int c0 = tc * CPT;
    bool ok0 = r0 < M, ok1 = r1 < M;
    const float4* X4 = (const float4*)X;
    const float4 z4 = make_float4(0.f, 0.f, 0.f, 0.f);

    float acc[2][CPT];
#pragma unroll
    for (int rr = 0; rr < 2; ++rr)
#pragma unroll
        for (int j = 0; j < CPT; ++j) acc[rr][j] = 0.f;

#pragma unroll 2
    for (int k4 = 0; k4 < KF4; ++k4) {
        float4 xa = ok0 ? X4[(size_t)r0 * KF4 + k4] : z4;
        float4 xb = ok1 ? X4[(size_t)r1 * KF4 + k4] : z4;
        float ar[4] = {xa.x, xa.y, xa.z, xa.w};
        float br[4] = {xb.x, xb.y, xb.z, xb.w};
#pragma unroll
        for (int j = 0; j < 4; ++j) {
            float va = ar[j], vb = br[j];
            if (RELU_IN) {
                float bv = bb[4 * k4 + j];
                va = fmaxf(va + bv, 0.f);
                vb = fmaxf(vb + bv, 0.f);
            }
#pragma unroll
            for (int q = 0; q < CPT / 4; ++q) {
                float4 wv = *(const float4*)&w[(4 * k4 + j) * NC + c0 + 4 * q];
                acc[0][q*4+0] = fmaf(va, wv.x, acc[0][q*4+0]);
                acc[0][q*4+1] = fmaf(va, wv.y, acc[0][q*4+1]);
                acc[0][q*4+2] = fmaf(va, wv.z, acc[0][q*4+2]);
                acc[0][q*4+3] = fmaf(va, wv.w, acc[0][q*4+3]);
                acc[1][q*4+0] = fmaf(vb, wv.x, acc[1][q*4+0]);
                acc[1][q*4+1] = fmaf(vb, wv.y, acc[1][q*4+1]);
                acc[1][q*4+2] = fmaf(vb, wv.z, acc[1][q*4+2]);
                acc[1][q*4+3] = fmaf(vb, wv.w, acc[1][q*4+3]);
            }
        }
    }
#pragma unroll
    for (int rr = 0; rr < 2; ++rr) {
        int gr = r0 + rr;
        if (gr >= M) continue;
        float d = dinv[gr];
#pragma unroll
        for (int q = 0; q < CPT / 4; ++q) {
            float4 o;
            o.x = acc[rr][q*4+0] * d; o.y = acc[rr][q*4+1] * d;
            o.z = acc[rr][q*4+2] * d; o.w = acc[rr][q*4+3] * d;
            ((float4*)H)[((size_t)gr * NC + c0) / 4 + q] = o;
        }
    }
}

// out[i,:] = dinv[i] * (Hs[i,:] + sum_{e in row i} Hs[src_e,:]) (+ b)
template <int NC, bool BIAS>
__global__ void k_agg(const float* __restrict__ Hs, const int* __restrict__ row_ptr,
                      const int* __restrict__ srcsort, const float* __restrict__ dinv,
                      const float* __restrict__ bias, float* __restrict__ out) {
    constexpr int Q = NC / 4;
    int idx = blockIdx.x * blockDim.x + threadIdx.x;
    if (idx >= NN * Q) return;
    int r = idx / Q, q = idx - r * Q;
    const float4* H4 = (const float4*)Hs;
    float4 a = H4[(size_t)r * Q + q];                   // self-loop term
    float ax = a.x, ay = a.y, az = a.z, aw = a.w;
    int e0 = row_ptr[r], e1 = row_ptr[r + 1];
    for (int e = e0; e < e1; ++e) {
        int s = srcsort[e];
        float4 v = H4[(size_t)s * Q + q];
        ax += v.x; ay += v.y; az += v.z; aw += v.w;
    }
    float d = dinv[r];
    ax *= d; ay *= d; az *= d; aw *= d;
    if (BIAS) {
        const float4* b4 = (const float4*)bias;
        float4 bv = b4[q];
        ax += bv.x; ay += bv.y; az += bv.z; aw += bv.w;
    }
    float4 o = {ax, ay, az, aw};
    ((float4*)out)[(size_t)r * Q + q] = o;
}

extern "C" void kernel_launch(void* const* d_in, const int* in_sizes, int n_in,
                              void* d_out, int out_size, void* d_ws, size_t ws_size,
                              hipStream_t stream) {
    const float* x  = (const float*)d_in[0];
    const int*   ei = (const int*)d_in[1];   // [2,NE] int32
    const float* W1 = (const float*)d_in[2];
    const float* b1 = (const float*)d_in[3];
    const float* W2 = (const float*)d_in[4];
    const float* b2 = (const float*)d_in[5];
    float* out = (float*)d_out;

    const int* src = ei;
    const int* dst = ei + NE;

    char* p = (char*)d_ws;
    auto take = [&](size_t elems) { void* q = p; p += ((elems * 4 + 255) & ~255ull); return q; };
    int*   bcnt    = (int*)take(NBUCK);
    int*   bbase   = (int*)take(NBUCK + 1);
    int*   gcursor = (int*)take(NBUCK);
    int*   row_ptr = (int*)take(NN + 1);
    float* dinv    = (float*)take(NN);
    int*   srcsort = (int*)take(NE);
    float* Hs      = (float*)take((size_t)NN * 48);
    float* agg1    = (float*)take((size_t)NN * 48);
    int*   packed  = (int*)agg1;   // alias: packed dead before agg1 is written
    float* Hs2     = Hs;           // Hs dead after agg1

    const int B = 256;
    const int GB = (NN + 127) / 128;   // 782 gemm blocks
    // --- dst-sort of edges ---
    k_zero_b<<<1, 1024, 0, stream>>>(bcnt);
    k_hist<<<PART_G, PART_B, 0, stream>>>(dst, bcnt);
    k_scan<<<1, 1024, 0, stream>>>(bcnt, bbase, gcursor, row_ptr);
    k_part<<<PART_G, PART_B, 0, stream>>>(src, dst, gcursor, packed);
    k_bsort<<<NBUCK, 256, 0, stream>>>(packed, bbase, srcsort, row_ptr, dinv);

    // --- layer 1 ---
    k_gemm<64, 48, 12, false><<<GB, 256, 0, stream>>>(x, W1, nullptr, dinv, Hs, NN);
    k_agg<48, false><<<(NN * 12 + B - 1) / B, B, 0, stream>>>(Hs, row_ptr, srcsort, dinv, nullptr, agg1);

    // --- layer 2 (bias1+relu fused into GEMM input read) ---
    k_gemm<48, 32, 8, true><<<GB, 256, 0, stream>>>(agg1, W2, b1, dinv, Hs2, NN);
    k_agg<32, true><<<(NN * 8 + B - 1) / B, B, 0, stream>>>(Hs2, row_ptr, srcsort, dinv, b2, out);
}